// Round 12
// baseline (1991.995 us; speedup 1.0000x reference)
//
#include <hip/hip_runtime.h>
#include <cstdint>

typedef _Float16 f16;
typedef __attribute__((ext_vector_type(2))) _Float16 f16x2;
typedef __attribute__((ext_vector_type(8))) _Float16 f16x8;
typedef __attribute__((ext_vector_type(4))) float f32x4;
typedef __attribute__((ext_vector_type(2))) float f32x2;
typedef __attribute__((ext_vector_type(8))) unsigned short us8;
typedef __attribute__((ext_vector_type(4))) int i32x4;

#define NB   32
#define TIN  1600
#define CIN  80
#define DH   512
#define NV   1000
#define NU   200
#define TXP  1604
#define THP  804
#define EPSB 1e-3f
#define EWG  248          // worker blocks (8 GRU + 248 workers = 256)
#define UBLK 25           // 25 u-blocks of 8

// ---- write-through (coherence point) stores — R5/R11-proven
__device__ __forceinline__ void st_sys_f16(f16* p, float v)
{
    f16 h = (f16)v; short s; __builtin_memcpy(&s, &h, 2); int si = (int)s;
    asm volatile("global_store_short %0, %1, off sc0 sc1" :: "v"(p), "v"(si) : "memory");
}
__device__ __forceinline__ void st_sys_f16x2(f16* p, float a, float b)
{
    f16x2 h; h.x = (f16)a; h.y = (f16)b; int v; __builtin_memcpy(&v, &h, 4);
    asm volatile("global_store_dword %0, %1, off sc0 sc1" :: "v"(p), "v"(v) : "memory");
}
__device__ __forceinline__ void st_sys_i32(int* p, int v)
{
    asm volatile("global_store_dword %0, %1, off sc0 sc1" :: "v"(p), "v"(v) : "memory");
}

// R5-proven poll: 8 words, loads+waitcnt in ONE asm blob (race-free by construction)
__device__ __forceinline__ void poll8(const int* fl, int target)
{
    i32x4 a, b;
    while (true) {
        asm volatile("global_load_dwordx4 %0, %2, off sc1\n\t"
                     "global_load_dwordx4 %1, %3, off sc1\n\t"
                     "s_waitcnt vmcnt(0)"
                     : "=&v"(a), "=&v"(b) : "v"(fl), "v"(fl + 4) : "memory");
        if (a.x == target && a.y == target && a.z == target && a.w == target &&
            b.x == target && b.y == target && b.z == target && b.w == target) break;
        __builtin_amdgcn_s_sleep(1);
    }
}

__device__ __forceinline__ float fast_tanh(float x)
{
    return 1.f - 2.f / (__expf(2.f * x) + 1.f);
}

// release/acquire counter barrier among the EWG workers (R3/R11-proven)
__device__ __forceinline__ void wbar(int* slot)
{
    __syncthreads();
    if (threadIdx.x == 0) {
        __hip_atomic_fetch_add(slot, 1, __ATOMIC_RELEASE, __HIP_MEMORY_SCOPE_AGENT);
        while (__hip_atomic_load(slot, __ATOMIC_RELAXED, __HIP_MEMORY_SCOPE_AGENT) < EWG)
            __builtin_amdgcn_s_sleep(8);
        (void)__hip_atomic_load(slot, __ATOMIC_ACQUIRE, __HIP_MEMORY_SCOPE_AGENT);
    }
    __syncthreads();
}

// ---------------------------------------------------------------- init
__global__ void init_zero(float* gsum, float* gsumsq, int* flags, int* cflag,
                          int* lcnt, f16* xpad, f16* hbufA, f16* hbufB)
{
    int tid = blockIdx.x * 256 + threadIdx.x;
    int stride = gridDim.x * 256;
    if (blockIdx.x == 0) {
        if (threadIdx.x < 80) { gsum[threadIdx.x] = 0.f; gsumsq[threadIdx.x] = 0.f; }
        if (threadIdx.x >= 128 && threadIdx.x < 136) lcnt[threadIdx.x - 128] = 0;
    }
    for (int i = tid; i < NU * 8; i += stride) flags[i] = 0;
    for (int i = tid; i < UBLK * 32; i += stride) cflag[i] = 0;
    for (int i = tid; i < NB * 4 * CIN; i += stride) {
        int b = i / (4 * CIN), rr = (i / CIN) % 4, c = i % CIN;
        int row = (rr == 0) ? 0 : (1600 + rr);
        xpad[((long)b * TXP + row) * CIN + c] = (f16)0.f;
    }
    for (int i = tid; i < 2 * NB * 4 * DH; i += stride) {
        int q = i; int buf = q / (NB * 4 * DH); q %= NB * 4 * DH;
        int b = q / (4 * DH); int rr = (q / DH) % 4; int dd = q % DH;
        int row = (rr < 2) ? rr : (800 + rr);
        f16* hb = buf ? hbufB : hbufA;
        hb[((long)b * THP + row) * DH + dd] = (f16)0.f;
    }
}

// ---------------------------------------------------------------- transpose f32 -> f16
__global__ void transpose_f32_f16(const float* __restrict__ in, int R, int C,
                                  f16* __restrict__ out, int outRows, int outCols)
{
    __shared__ float t[32][33];
    int c0 = blockIdx.x * 32, r0 = blockIdx.y * 32;
    int x = threadIdx.x & 31, y = threadIdx.x >> 5;
    for (int i = y; i < 32; i += 8) {
        int r = r0 + i, c = c0 + x;
        t[i][x] = (r < R && c < C) ? in[(long)r * C + c] : 0.0f;
    }
    __syncthreads();
    for (int i = y; i < 32; i += 8) {
        int orow = c0 + i, ocol = r0 + x;
        if (orow < outRows && ocol < outCols)
            out[(long)orow * outCols + ocol] = (f16)t[x][i];
    }
}

// ---------------------------------------------------------------- batchnorm
__global__ void bn_stats(const float* __restrict__ x, float* gsum, float* gsumsq)
{
    __shared__ float ls[240], ls2[240];
    const float* base = x + (long)blockIdx.x * 200 * CIN;
    int tid = threadIdx.x;
    if (tid < 240) {
        int c = tid % 80, rg = tid / 80;
        float s = 0.f, s2 = 0.f;
        for (int r = rg; r < 200; r += 3) {
            float v = base[r * CIN + c];
            s += v; s2 += v * v;
        }
        ls[tid] = s; ls2[tid] = s2;
    }
    __syncthreads();
    if (tid < 80) {
        atomicAdd(&gsum[tid],   ls[tid] + ls[tid + 80] + ls[tid + 160]);
        atomicAdd(&gsumsq[tid], ls2[tid] + ls2[tid + 80] + ls2[tid + 160]);
    }
}

__global__ void bn_apply(const float* __restrict__ x, const float* __restrict__ gsum,
                         const float* __restrict__ gsumsq, const float* __restrict__ gamma,
                         const float* __restrict__ beta, f16* __restrict__ xpad)
{
    long idx = (long)blockIdx.x * 256 + threadIdx.x;
    if (idx >= (long)NB * TIN * CIN) return;
    int c = (int)(idx % CIN);
    long bt = idx / CIN;
    int t = (int)(bt % TIN); int b = (int)(bt / TIN);
    float mean = gsum[c] * (1.f / 51200.f);
    float var  = gsumsq[c] * (1.f / 51200.f) - mean * mean;
    float sc = gamma[c] * rsqrtf(var + EPSB);
    float sh = beta[c] - mean * sc;
    xpad[((long)b * TXP + t + 1) * CIN + c] = (f16)(x[idx] * sc + sh);
}

// ---------------------------------------------------------------- encoder layer worker
__device__ void enc_layer(int eb, int tid,
                          const f16* __restrict__ Ab, long strideA, long slabA,
                          const f16* __restrict__ Bb, long strideB,
                          int Kchunks, const float* __restrict__ bias,
                          const f16* __restrict__ resid, f16* __restrict__ outH,
                          long slabRO, f16 (*As)[72], f16 (*Bs)[72])
{
    const int lane = tid & 63, wv = tid >> 6;
    const int lm = lane & 15, lk = lane >> 4;
    const int srow = tid >> 3, scol = (tid & 7) * 8;
    f32x4 vzero = {0.f, 0.f, 0.f, 0.f};

    for (int t = eb; t < 1664; t += EWG) {
        int b = t / 52, rem = t - b * 52;
        int m0 = (rem >> 2) * 64, n0 = (rem & 3) * 128;
        const f16* Abase = Ab + (long)b * slabA;

        f32x4 acc[4][2];
#pragma unroll
        for (int i = 0; i < 4; i++) { acc[i][0] = vzero; acc[i][1] = vzero; }

        for (int kc = 0; kc < Kchunks; kc++) {
            int kb = kc * 64;
#pragma unroll
            for (int p = 0; p < 2; p++) {
                int r = srow + p * 32;
                int m = m0 + r; if (m > 799) m = 799;
                *(us8*)&As[r][scol] = *(const us8*)(Abase + (long)m * strideA + kb + scol);
            }
#pragma unroll
            for (int p = 0; p < 4; p++) {
                int r = srow + p * 32;
                *(us8*)&Bs[r][scol] = *(const us8*)(Bb + (long)(n0 + r) * strideB + kb + scol);
            }
            __syncthreads();
#pragma unroll
            for (int ks = 0; ks < 2; ks++) {
                f16x8 af[4], bf[2];
#pragma unroll
                for (int mt = 0; mt < 4; mt++)
                    af[mt] = *(const f16x8*)&As[mt * 16 + lm][ks * 32 + lk * 8];
#pragma unroll
                for (int nt = 0; nt < 2; nt++)
                    bf[nt] = *(const f16x8*)&Bs[wv * 32 + nt * 16 + lm][ks * 32 + lk * 8];
#pragma unroll
                for (int mt = 0; mt < 4; mt++)
#pragma unroll
                    for (int nt = 0; nt < 2; nt++)
                        acc[mt][nt] = __builtin_amdgcn_mfma_f32_16x16x32_f16(af[mt], bf[nt], acc[mt][nt], 0, 0, 0);
            }
            __syncthreads();
        }
#pragma unroll
        for (int mt = 0; mt < 4; mt++) {
#pragma unroll
            for (int nt = 0; nt < 2; nt++) {
                int n = n0 + wv * 32 + nt * 16 + lm;
#pragma unroll
                for (int reg = 0; reg < 4; reg++) {
                    int m = m0 + mt * 16 + lk * 4 + reg;
                    if (m >= 800) continue;
                    float v = acc[mt][nt][reg] + bias[n];
                    v = v > 0.f ? v : 0.f;
                    if (resid) v += (float)resid[(long)b * slabRO + (long)(2 + m) * DH + n];
                    outH[(long)b * slabRO + (long)(2 + m) * DH + n] = (f16)v;
                }
            }
        }
    }
}

// ---------------------------------------------------------------- decode task1: scores+softmax+ctx for (ublock k, batch b)
__device__ void task1(int k, int b, int tid, const f16* __restrict__ Hc_c,
                      f16* __restrict__ Hc, const f16* __restrict__ encb,
                      const int* __restrict__ flags, int* __restrict__ cflag,
                      f16 (*hA)[512], float (*sc)[808])
{
    const int lane = tid & 63, wv = tid >> 6;
    const int lm = lane & 15, lk = lane >> 4;

    poll8(flags + (8 * k + 7) * 8, 8 * k + 8);   // all 8 GRU WGs past step 8k+7

    // stage Hc[8k..8k+7][b][0:512] -> hA (plain loads; lines fresh per protocol)
    for (int c = tid; c < 512; c += 256) {
        int u = c >> 6, d = (c & 63) * 8;
        *(us8*)&hA[u][d] = *(const us8*)(Hc_c + ((long)(8 * k + u) * 32 + b) * 1024 + d);
    }
    __syncthreads();

    // scores MFMA: A = hA (m=u), B = enc rows (n=t), K=512
    f16x8 af[16];
#pragma unroll
    for (int ks = 0; ks < 16; ks++)
        af[ks] = *(const f16x8*)&hA[lm & 7][ks * 32 + lk * 8];

    for (int tt = wv; tt < 50; tt += 4) {
        f32x4 acc = {0.f, 0.f, 0.f, 0.f};
        const f16* bb = encb + (long)(tt * 16 + lm) * DH + lk * 8;
#pragma unroll
        for (int ks = 0; ks < 16; ks++) {
            f16x8 bf = *(const f16x8*)(bb + ks * 32);
            acc = __builtin_amdgcn_mfma_f32_16x16x32_f16(af[ks], bf, acc, 0, 0, 0);
        }
#pragma unroll
        for (int reg = 0; reg < 4; reg++) {
            int row = lk * 4 + reg;
            if (row < 8) sc[row][tt * 16 + lm] = acc[reg];
        }
    }
    __syncthreads();

    // softmax rows (wave wv does rows wv, wv+4)
    for (int rr = wv; rr < 8; rr += 4) {
        float mx = -1e30f;
        for (int i = lane; i < 800; i += 64) mx = fmaxf(mx, sc[rr][i]);
#pragma unroll
        for (int off = 32; off; off >>= 1) mx = fmaxf(mx, __shfl_xor(mx, off));
        float sum = 0.f;
        for (int i = lane; i < 800; i += 64) {
            float e = __expf(sc[rr][i] - mx);
            sc[rr][i] = e; sum += e;
        }
#pragma unroll
        for (int off = 32; off; off >>= 1) sum += __shfl_xor(sum, off);
        float inv = 1.f / sum;
        for (int i = lane; i < 800; i += 64) sc[rr][i] *= inv;
    }
    __syncthreads();

    // ctx: thread owns d0=tid*2; alpha broadcast from LDS
    int d0 = tid * 2;
    float c0[8], c1[8];
#pragma unroll
    for (int u = 0; u < 8; u++) { c0[u] = 0.f; c1[u] = 0.f; }
    const f16* ep = encb + d0;
    for (int t = 0; t < 800; t++) {
        f16x2 e = *(const f16x2*)(ep + (long)t * DH);
        float f0 = (float)e.x, f1 = (float)e.y;
#pragma unroll
        for (int u = 0; u < 8; u++) {
            float a = sc[u][t];
            c0[u] += a * f0; c1[u] += a * f1;
        }
    }
#pragma unroll
    for (int u = 0; u < 8; u++)
        st_sys_f16x2(&Hc[((long)(8 * k + u) * 32 + b) * 1024 + 512 + d0], c0[u], c1[u]);

    asm volatile("s_waitcnt vmcnt(0)" ::: "memory");
    __syncthreads();
    if (tid == 0) st_sys_i32(&cflag[k * 32 + b], 1);
}

// ---------------------------------------------------------------- decode task2: fc tile for (ublock k, vtile v)
__device__ void task2(int k, int v, int tid, const f16* __restrict__ Hc_c,
                      const f16* __restrict__ fcT, const float* __restrict__ fcb,
                      float* __restrict__ out, const int* __restrict__ cflag,
                      f16 (*As)[72], f16 (*Bs)[72])
{
    const int lane = tid & 63, wv = tid >> 6;
    const int lm = lane & 15, lk = lane >> 4;
    const int srow = tid >> 3, scol = (tid & 7) * 8;
    const int n0 = v * 128;
    const f16* Abase = Hc_c + (long)k * 256 * 1024;
    f32x4 vzero = {0.f, 0.f, 0.f, 0.f};

    poll8(cflag + k * 32,      1);
    poll8(cflag + k * 32 + 8,  1);
    poll8(cflag + k * 32 + 16, 1);
    poll8(cflag + k * 32 + 24, 1);
    __syncthreads();

    for (int mt4 = 0; mt4 < 4; mt4++) {
        int m0 = mt4 * 64;
        f32x4 acc[4][2];
#pragma unroll
        for (int i = 0; i < 4; i++) { acc[i][0] = vzero; acc[i][1] = vzero; }

        for (int kc = 0; kc < 16; kc++) {
            int kb = kc * 64;
#pragma unroll
            for (int p = 0; p < 2; p++) {
                int r = srow + p * 32;
                *(us8*)&As[r][scol] = *(const us8*)(Abase + (long)(m0 + r) * 1024 + kb + scol);
            }
#pragma unroll
            for (int p = 0; p < 4; p++) {
                int r = srow + p * 32;
                *(us8*)&Bs[r][scol] = *(const us8*)(fcT + (long)(n0 + r) * 1024 + kb + scol);
            }
            __syncthreads();
#pragma unroll
            for (int ks = 0; ks < 2; ks++) {
                f16x8 af[4], bf[2];
#pragma unroll
                for (int mt = 0; mt < 4; mt++)
                    af[mt] = *(const f16x8*)&As[mt * 16 + lm][ks * 32 + lk * 8];
#pragma unroll
                for (int nt = 0; nt < 2; nt++)
                    bf[nt] = *(const f16x8*)&Bs[wv * 32 + nt * 16 + lm][ks * 32 + lk * 8];
#pragma unroll
                for (int mt = 0; mt < 4; mt++)
#pragma unroll
                    for (int nt = 0; nt < 2; nt++)
                        acc[mt][nt] = __builtin_amdgcn_mfma_f32_16x16x32_f16(af[mt], bf[nt], acc[mt][nt], 0, 0, 0);
            }
            __syncthreads();
        }
#pragma unroll
        for (int mt = 0; mt < 4; mt++) {
#pragma unroll
            for (int nt = 0; nt < 2; nt++) {
                int n = n0 + wv * 32 + nt * 16 + lm;
                if (n >= NV) continue;
#pragma unroll
                for (int reg = 0; reg < 4; reg++) {
                    int m = m0 + mt * 16 + lk * 4 + reg;
                    int u = 8 * k + (m >> 5), b = m & 31;
                    out[((long)b * NU + u) * 1000 + n] = acc[mt][nt][reg] + fcb[n];
                }
            }
        }
    }
}

// ---------------------------------------------------------------- fused: 8 GRU WGs + 248 workers (encoder then streamed decode)
__launch_bounds__(256, 1)
__global__ void enc_gru(const f16* __restrict__ wrecT, const float* __restrict__ gk,
                        const float* __restrict__ gbias, const int* __restrict__ ytrue,
                        f16* __restrict__ Hc, int* __restrict__ flags, int* __restrict__ cflag,
                        const f16* __restrict__ xpad, const f16* __restrict__ w0T,
                        const float* __restrict__ b0, const f16* __restrict__ tcrT,
                        const float* __restrict__ tcrb,
                        f16* __restrict__ hbufA, f16* __restrict__ hbufB,
                        const f16* __restrict__ fcT, const float* __restrict__ fcb,
                        float* __restrict__ out, int* __restrict__ lcnt)
{
    const int tid = threadIdx.x;

    if (blockIdx.x < 8) {
        // ==================== GRU (R5 protocol; flag now also at u=199) ====================
        __shared__ int yl[NU * 32];
        const int lane = tid & 63, wv = tid >> 6;
        const int gw = (int)blockIdx.x * 4 + wv;
        const int lm = lane & 15, lk = lane >> 4;
        const int j = gw * 16 + lm;

        for (int i = tid; i < NU * 32; i += 256) {
            int b = i / NU, u = i - b * NU;
            yl[u * 32 + b] = ytrue[b * 201 + u];
        }

        f16x8 wf[3][16];
#pragma unroll
        for (int g = 0; g < 3; g++)
#pragma unroll
            for (int ks = 0; ks < 16; ks++)
                wf[g][ks] = *(const f16x8*)&wrecT[(long)(g * 512 + j) * 512 + ks * 32 + lk * 8];

        const float biz = gbias[j],        bir = gbias[512 + j],        bic = gbias[1024 + j];
        const float brz = gbias[1536 + j], brr = gbias[1536 + 512 + j], brc = gbias[1536 + 1024 + j];
        f32x4 vzero = {0.f, 0.f, 0.f, 0.f};

        __syncthreads();

        float hold[8];
        float nxz[8], nxr[8], nxh[8], mxz[8], mxr[8], mxh[8];
#pragma unroll
        for (int s = 0; s < 8; s++) {
            hold[s] = 0.f;
            int b = ((s >> 2) << 4) + lk * 4 + (s & 3);
            const float* gkr = gk + (long)yl[b] * 1536;
            nxz[s] = gkr[j]; nxr[s] = gkr[512 + j]; nxh[s] = gkr[1024 + j];
        }

        for (int u = 0; u < NU; u++) {
            int up = (u < NU - 1) ? u + 1 : u;
#pragma unroll
            for (int s = 0; s < 8; s++) {
                int b = ((s >> 2) << 4) + lk * 4 + (s & 3);
                const float* gkr = gk + (long)yl[up * 32 + b] * 1536;
                mxz[s] = gkr[j]; mxr[s] = gkr[512 + j]; mxh[s] = gkr[1024 + j];
            }

            f32x4 acc[3][2];
#pragma unroll
            for (int g = 0; g < 3; g++) { acc[g][0] = vzero; acc[g][1] = vzero; }

            if (u > 0) {
                poll8(flags + (u - 1) * 8, u);
                const f16* hrow = Hc + (long)(u - 1) * 32 * 1024 + lk * 8;
#pragma unroll
                for (int ks = 0; ks < 16; ks++) {
                    f16x8 a0 = *(const f16x8*)(hrow + (long)lm * 1024 + ks * 32);
                    f16x8 a1 = *(const f16x8*)(hrow + (long)(16 + lm) * 1024 + ks * 32);
#pragma unroll
                    for (int g = 0; g < 3; g++) {
                        acc[g][0] = __builtin_amdgcn_mfma_f32_16x16x32_f16(a0, wf[g][ks], acc[g][0], 0, 0, 0);
                        acc[g][1] = __builtin_amdgcn_mfma_f32_16x16x32_f16(a1, wf[g][ks], acc[g][1], 0, 0, 0);
                    }
                }
            }

#pragma unroll
            for (int mt = 0; mt < 2; mt++) {
#pragma unroll
                for (int reg = 0; reg < 4; reg++) {
                    int s = mt * 4 + reg;
                    int b = mt * 16 + lk * 4 + reg;
                    float hz = acc[0][mt][reg] + brz;
                    float hr = acc[1][mt][reg] + brr;
                    float hh = acc[2][mt][reg] + brc;
                    float z = 1.f / (1.f + __expf(-(nxz[s] + biz + hz)));
                    float r = 1.f / (1.f + __expf(-(nxr[s] + bir + hr)));
                    float cd = fast_tanh(nxh[s] + bic + r * hh);
                    float hnew = z * hold[s] + (1.f - z) * cd;
                    hold[s] = hnew;
                    st_sys_f16(&Hc[((long)u * 32 + b) * 1024 + j], hnew);
                }
            }
#pragma unroll
            for (int s = 0; s < 8; s++) { nxz[s] = mxz[s]; nxr[s] = mxr[s]; nxh[s] = mxh[s]; }

            asm volatile("s_waitcnt vmcnt(0)" ::: "memory");
            __syncthreads();
            if (tid == 0) st_sys_i32(&flags[u * 8 + (int)blockIdx.x], u + 1);
        }
        asm volatile("s_waitcnt vmcnt(0)" ::: "memory");
        return;
    }

    // ==================== workers ====================
    __shared__ char smraw[34048] __attribute__((aligned(16)));
    f16 (*As)[72]   = (f16(*)[72])smraw;                 // 9216 B
    f16 (*Bs)[72]   = (f16(*)[72])(smraw + 9216);        // 18432 B
    f16 (*hA)[512]  = (f16(*)[512])smraw;                // 8192 B (task1 view)
    float (*sc)[808]= (float(*)[808])(smraw + 8192);     // 25856 B (task1 view)

    const int eb = (int)blockIdx.x - 8;

    // ---- encoder phase
    enc_layer(eb, tid, xpad, 160, (long)TXP * CIN, w0T, 448, 7, b0,
              nullptr, hbufA, (long)THP * DH, As, Bs);

    const f16* tin = hbufA; f16* tout = hbufB;
    for (int L = 0; L < 4; L++) {
        wbar(&lcnt[L]);
        enc_layer(eb, tid, tin, 512, (long)THP * DH, tcrT + (size_t)L * 512 * 2560, 2560,
                  40, tcrb + L * 512, tin, tout, (long)THP * DH, As, Bs);
        const f16* t2 = tout; tout = (f16*)tin; tin = t2;
    }
    wbar(&lcnt[4]);               // encoder fully published (enc = hbufA)
    const f16* encA = hbufA;

    // ---- streamed decode: 25 blocks x (32 task1 + 8 task2), topological order
    for (int t = eb; t < UBLK * 40; t += EWG) {
        int k = t / 40, r = t - k * 40;
        if (r < 32) {
            task1(k, r, tid, Hc, Hc, encA + ((long)r * THP + 2) * DH, flags, cflag, hA, sc);
        } else {
            task2(k, r - 32, tid, Hc, fcT, fcb, out, cflag, As, Bs);
        }
        __syncthreads();
    }
}

// ---------------------------------------------------------------- row softmax in place
__global__ void row_softmax(float* __restrict__ base, int len)
{
    float* s = base + (long)blockIdx.x * len;
    int tid = threadIdx.x;
    float v[4]; float mx = -1e30f;
#pragma unroll
    for (int i = 0; i < 4; i++) {
        int idx = tid + i * 256;
        v[i] = (idx < len) ? s[idx] : -1e30f;
        mx = fmaxf(mx, v[i]);
    }
#pragma unroll
    for (int off = 32; off; off >>= 1) mx = fmaxf(mx, __shfl_xor(mx, off));
    __shared__ float red[4], red2[4];
    if ((tid & 63) == 0) red[tid >> 6] = mx;
    __syncthreads();
    mx = fmaxf(fmaxf(red[0], red[1]), fmaxf(red[2], red[3]));
    float sum = 0.f;
#pragma unroll
    for (int i = 0; i < 4; i++) { v[i] = __expf(v[i] - mx); sum += v[i]; }
#pragma unroll
    for (int off = 32; off; off >>= 1) sum += __shfl_xor(sum, off);
    if ((tid & 63) == 0) red2[tid >> 6] = sum;
    __syncthreads();
    sum = red2[0] + red2[1] + red2[2] + red2[3];
    float inv = 1.f / sum;
#pragma unroll
    for (int i = 0; i < 4; i++) {
        int idx = tid + i * 256;
        if (idx < len) s[idx] = v[i] * inv;
    }
}

// ---------------------------------------------------------------- launcher
extern "C" void kernel_launch(void* const* d_in, const int* in_sizes, int n_in,
                              void* d_out, int out_size, void* d_ws, size_t ws_size,
                              hipStream_t stream)
{
    const float* x     = (const float*)d_in[0];
    const int*   ytrue = (const int*)d_in[1];
    const float* gamma = (const float*)d_in[2];
    const float* beta  = (const float*)d_in[3];
    const float* w0    = (const float*)d_in[4];
    const float* b0    = (const float*)d_in[5];
    const float* tcrw  = (const float*)d_in[6];
    const float* tcrb  = (const float*)d_in[7];
    const float* gk    = (const float*)d_in[8];
    const float* grk   = (const float*)d_in[9];
    const float* gbias = (const float*)d_in[10];
    const float* fcw   = (const float*)d_in[11];
    const float* fcb   = (const float*)d_in[12];
    float* out = (float*)d_out;
    (void)in_sizes; (void)n_in; (void)out_size; (void)ws_size;

    char* ws = (char*)d_ws;
    size_t o = 0;
    auto alloc = [&](size_t bytes) { size_t r = o; o += (bytes + 255) & ~(size_t)255; return r; };
    f16*   xpad   = (f16*)(ws + alloc((size_t)NB * TXP * CIN * 2));
    f16*   hbufA  = (f16*)(ws + alloc((size_t)NB * THP * DH * 2));
    f16*   hbufB  = (f16*)(ws + alloc((size_t)NB * THP * DH * 2));
    f16*   Hc     = (f16*)(ws + alloc((size_t)NU * NB * 1024 * 2));
    f16*   w0T    = (f16*)(ws + alloc((size_t)512 * 448 * 2));
    f16*   tcrT   = (f16*)(ws + alloc((size_t)4 * 512 * 2560 * 2));
    f16*   wrecT  = (f16*)(ws + alloc((size_t)1536 * 512 * 2));
    f16*   fcT    = (f16*)(ws + alloc((size_t)1024 * 1024 * 2));
    float* gsum   = (float*)(ws + alloc(80 * 4));
    float* gsumsq = (float*)(ws + alloc(80 * 4));
    int*   flags  = (int*)(ws + alloc(NU * 8 * 4));
    int*   cflag  = (int*)(ws + alloc(UBLK * 32 * 4));
    int*   lcnt   = (int*)(ws + alloc(64));

    init_zero<<<64, 256, 0, stream>>>(gsum, gsumsq, flags, cflag, lcnt, xpad, hbufA, hbufB);
    transpose_f32_f16<<<dim3(16, 14), 256, 0, stream>>>(w0, 400, 512, w0T, 512, 448);
    for (int i = 0; i < 4; i++)
        transpose_f32_f16<<<dim3(16, 80), 256, 0, stream>>>(tcrw + (size_t)i * 2560 * 512, 2560, 512,
                                                            tcrT + (size_t)i * 512 * 2560, 512, 2560);
    transpose_f32_f16<<<dim3(48, 16), 256, 0, stream>>>(grk, 512, 1536, wrecT, 1536, 512);
    transpose_f32_f16<<<dim3(32, 32), 256, 0, stream>>>(fcw, 1024, 1000, fcT, 1024, 1024);

    bn_stats<<<256, 256, 0, stream>>>(x, gsum, gsumsq);
    bn_apply<<<16000, 256, 0, stream>>>(x, gsum, gsumsq, gamma, beta, xpad);

    // fused: GRU + encoder + streamed attention/fc tail
    enc_gru<<<8 + EWG, 256, 0, stream>>>(wrecT, gk, gbias, ytrue, Hc, flags, cflag,
                                         xpad, w0T, b0, tcrT, tcrb, hbufA, hbufB,
                                         fcT, fcb, out, lcnt);

    row_softmax<<<6400, 256, 0, stream>>>(out, 1000);
}